// Round 6
// baseline (71.772 us; speedup 1.0000x reference)
//
#include <hip/hip_runtime.h>

#define IN_CH 16
#define OUT_CH 32
#define NUM_INPUTS 144   // IN_CH * 3 * 3
#define H_ 32
#define W_ 32
#define TILE_H 8
#define LDS_H 10         // TILE_H + 2 halo
#define LDS_W 34         // 34 mod 32 == 2 -> exactly 2 lanes/bank (free)
#define CHW (LDS_H * LDS_W)

typedef __attribute__((ext_vector_type(2))) float f32x2;

// ---------------------------------------------------------------------------
// Single fused kernel. Grid (32 spatial tiles, 8 channel-quads) = 256 blocks
// (1/CU), 256 threads = 4 waves. Thread = 2 adjacent rows x 2 channels; block
// covers 8 rows x 32 cols x 4 channels x all 16 input channels -> every
// output written by exactly one thread: NO split-K, NO atomics, NO memset,
// NO prep kernel, NO workspace, NO cross-XCD table round-trip.
//
// Phase 0a: stage 16ch x 10x34 zero-padded x tile in LDS (21.8 KB).
// Phase 0b: threads 0..143 build the block's table slice in LDS: per tap i,
//   params of y(p) = m0*p + b0 + (m1-m0)*max(p-p1,0)  (continuous at p1 ->
//   reproduces both clipped extrapolation tails exactly), for 4 channels,
//   laid out per (pair, tap) as 8 floats {P2,M2,D2,B2} = two float4s.
// Phase 1: fully-unrolled 144-tap loop. LDS only: per (c,kw) 4 patch
//   ds_read_b32 (2 lanes/bank, free) shared by both rows' kh windows; per
//   tap 2 wave-uniform ds_read_b128 (same-address broadcast, conflict-free).
//   b0 folded as one pk-add per tap (y = sum_i m0*p + b0 + dm*relu).
// ---------------------------------------------------------------------------
__global__ __launch_bounds__(256) void apc_fused(
        const float* __restrict__ x,
        const float* __restrict__ pos,
        const float* __restrict__ val,
        float* __restrict__ out) {
    __shared__ float lx[IN_CH * CHW];        // 5440 floats = 21.8 KB
    __shared__ float lt[2 * NUM_INPUTS * 8]; // 2304 floats =  9.2 KB

    int bx  = blockIdx.x;            // 0..31: b*4 + row_tile
    int b   = bx >> 2;
    int ho0 = (bx & 3) * TILE_H;
    int g   = blockIdx.y;            // channel-quad: o = 4g..4g+3
    int tid = threadIdx.x;

    // ---- Phase 0a: stage x tile with zero-padded halo (coalesced b32). ----
    for (int idx = tid; idx < IN_CH * CHW; idx += 256) {
        int c   = idx / CHW;
        int rem = idx - c * CHW;
        int r   = rem / LDS_W;
        int col = rem - r * LDS_W;
        int gr  = ho0 + r - 1;
        int gc  = col - 1;
        float v = 0.f;
        if ((unsigned)gr < (unsigned)H_ && (unsigned)gc < (unsigned)W_)
            v = x[((b * IN_CH + c) * H_ + gr) * W_ + gc];
        lx[idx] = v;
    }

    // ---- Phase 0b: build table slice in LDS (threads 0..143, 1 tap each).
    if (tid < NUM_INPUTS) {
        // pos/val[(i, o, p)]: this tap's 4-channel slice = 12 contiguous
        // floats at float offset i*96 + g*12 (byte 384i+48g, 16B-aligned).
        const float4* pp = (const float4*)(pos + tid * 96 + g * 12);
        const float4* vv = (const float4*)(val + tid * 96 + g * 12);
        float4 pA = pp[0], pB = pp[1], pC = pp[2];
        float4 vA = vv[0], vB = vv[1], vC = vv[2];
        float P[12] = {pA.x,pA.y,pA.z,pA.w, pB.x,pB.y,pB.z,pB.w, pC.x,pC.y,pC.z,pC.w};
        float V[12] = {vA.x,vA.y,vA.z,vA.w, vB.x,vB.y,vB.z,vB.w, vC.x,vC.y,vC.z,vC.w};
        float p1[4], m0[4], dm[4], b0[4];
        #pragma unroll
        for (int k = 0; k < 4; ++k) {
            float q0 = P[3*k], q1 = P[3*k+1], q2 = P[3*k+2];
            float w0 = V[3*k], w1 = V[3*k+1], w2 = V[3*k+2];
            float s0 = (w1 - w0) / (q1 - q0);
            float s1 = (w2 - w1) / (q2 - q1);
            p1[k] = q1; m0[k] = s0; dm[k] = s1 - s0; b0[k] = w0 - s0 * q0;
        }
        float4* d0 = (float4*)&lt[tid * 8];                   // pair 0: ch 4g,4g+1
        d0[0] = make_float4(p1[0], p1[1], m0[0], m0[1]);
        d0[1] = make_float4(dm[0], dm[1], b0[0], b0[1]);
        float4* d1 = (float4*)&lt[(NUM_INPUTS + tid) * 8];    // pair 1: ch 4g+2,4g+3
        d1[0] = make_float4(p1[2], p1[3], m0[2], m0[3]);
        d1[1] = make_float4(dm[2], dm[3], b0[2], b0[3]);
    }
    __syncthreads();

    // ---- Phase 1 -----------------------------------------------------------
    int col  = tid & 31;
    int trow = (tid >> 5) & 3;       // thread-row -> output rows 2*trow, 2*trow+1
    int pgrp = tid >> 7;             // 0: pair (4g,4g+1), 1: pair (4g+2,4g+3)
    int base = (2 * trow) * LDS_W + col;
    const float* tb = &lt[pgrp * NUM_INPUTS * 8];   // wave-uniform base

    f32x2 aA = {0,0}, hA = {0,0};    // row 2*trow
    f32x2 aB = {0,0}, hB = {0,0};    // row 2*trow+1
    f32x2 bb = {0,0};                // sum of per-tap b0 (added once, shared by rows)
    const f32x2 zz = {0.f, 0.f};

    #pragma unroll
    for (int c = 0; c < IN_CH; ++c) {
        #pragma unroll
        for (int kw = 0; kw < 3; ++kw) {
            // 4 shared input rows cover both output rows' 3-tap kh windows.
            float p0 = lx[c * CHW + base + 0 * LDS_W + kw];
            float p1 = lx[c * CHW + base + 1 * LDS_W + kw];
            float p2 = lx[c * CHW + base + 2 * LDS_W + kw];
            float p3 = lx[c * CHW + base + 3 * LDS_W + kw];
            float pa[4] = {p0, p1, p2, p3};
            #pragma unroll
            for (int kh = 0; kh < 3; ++kh) {
                int i = (c * 3 + kh) * 3 + kw;        // (c,kh,kw) tap ordering
                float4 q0 = *(const float4*)(tb + i * 8);      // P2, M2
                float4 q1 = *(const float4*)(tb + i * 8 + 4);  // D2, B2
                f32x2 P = {q0.x, q0.y}, M = {q0.z, q0.w};
                f32x2 D = {q1.x, q1.y}, B = {q1.z, q1.w};
                f32x2 qA = {pa[kh],     pa[kh]};
                f32x2 qB = {pa[kh + 1], pa[kh + 1]};
                aA = __builtin_elementwise_fma(M, qA, aA);
                hA = __builtin_elementwise_fma(D, __builtin_elementwise_max(qA - P, zz), hA);
                aB = __builtin_elementwise_fma(M, qB, aB);
                hB = __builtin_elementwise_fma(D, __builtin_elementwise_max(qB - P, zz), hB);
                bb += B;
            }
        }
    }

    f32x2 rA = aA + hA + bb;
    f32x2 rB = aB + hB + bb;

    int hoA = ho0 + 2 * trow;
    int o0  = 4 * g + 2 * pgrp;
    int HW  = H_ * W_;
    int ob  = ((b * OUT_CH + o0) * H_ + hoA) * W_ + col;
    out[ob         ] = rA.x;
    out[ob +     HW] = rA.y;
    out[ob + W_            ] = rB.x;
    out[ob + W_ +       HW ] = rB.y;
}

extern "C" void kernel_launch(void* const* d_in, const int* in_sizes, int n_in,
                              void* d_out, int out_size, void* d_ws, size_t ws_size,
                              hipStream_t stream) {
    const float* x   = (const float*)d_in[0];
    const float* pos = (const float*)d_in[1];
    const float* val = (const float*)d_in[2];

    dim3 grid(32, 8);
    apc_fused<<<grid, 256, 0, stream>>>(x, pos, val, (float*)d_out);
}

// Round 7
// 66.803 us; speedup vs baseline: 1.0744x; 1.0744x over previous
//
#include <hip/hip_runtime.h>

#define IN_CH 16
#define OUT_CH 32
#define NUM_INPUTS 144   // IN_CH * 3 * 3
#define H_ 32
#define W_ 32
#define TILE_H 4
#define LDS_H 6          // TILE_H + 2 halo
#define LDS_W 34         // 34 mod 32 == 2 -> exactly 2 lanes/bank (free)
#define CHW (LDS_H * LDS_W)   // 204

typedef __attribute__((ext_vector_type(2))) float f32x2;

// ---------------------------------------------------------------------------
// One fused kernel, occupancy-fixed vs R6. Grid (64 spatial, 8 quads) = 512
// blocks = 2/CU; block 256 thr = 4 waves -> 8 waves/CU = 2/SIMD (R6 had 1
// wave/SIMD: zero TLP to hide ds_read latency -> it ran ~2x its LDS floor).
// Thread = 2 rows x 2 ch x 8 input chans (2-way c-split IN-block, partials
// combined via 2KB LDS reduction -> still no atomics / memset / workspace).
//
// Phase 0a: stage 16ch x 6x34 zero-padded x tile (13 KB).
// Phase 0b: thr 0..143 build tap tables: y(p)=m0*p+b0+(m1-m0)*max(p-p1,0)
//   (continuous at p1 -> exact clipped-tail reproduction), split arrays:
//   ltPM[pair][tap] = (p1,p1',m0,m0') b128; ltD = (dm,dm') b64; ltB b64.
// Phase 1: per wave (fixed pair,cs): bb = sum of b0 over its 72 taps ONCE
//   (lane-parallel LDS + shfl_xor butterfly), then 72-tap unrolled loop:
//   1 b128 + 1 b64 broadcast + 4 patch b32 per (c,kw) group. All LDS.
// Epilogue: cs1 writes 4 partials to lred; cs0 adds and stores.
// ---------------------------------------------------------------------------
__global__ __launch_bounds__(256, 2) void apc_fused(
        const float* __restrict__ x,
        const float* __restrict__ pos,
        const float* __restrict__ val,
        float* __restrict__ out) {
    __shared__ float  lx[IN_CH * CHW];        // 13056 B
    __shared__ float4 ltPM[2 * NUM_INPUTS];   //  4608 B
    __shared__ f32x2  ltD [2 * NUM_INPUTS];   //  2304 B
    __shared__ f32x2  ltB [2 * NUM_INPUTS];   //  2304 B
    __shared__ float4 lred[128];              //  2048 B   (total 24.3 KB)

    int bx  = blockIdx.x;            // 0..63: b*8 + row_tile
    int b   = bx >> 3;
    int ho0 = (bx & 7) * TILE_H;
    int g   = blockIdx.y;            // channel-quad: o = 4g..4g+3
    int tid = threadIdx.x;

    // ---- Phase 0a: stage x tile with zero-padded halo. --------------------
    for (int idx = tid; idx < IN_CH * CHW; idx += 256) {
        int c   = idx / CHW;
        int rem = idx - c * CHW;
        int r   = rem / LDS_W;
        int col = rem - r * LDS_W;
        int gr  = ho0 + r - 1;
        int gc  = col - 1;
        float v = 0.f;
        if ((unsigned)gr < (unsigned)H_ && (unsigned)gc < (unsigned)W_)
            v = x[((b * IN_CH + c) * H_ + gr) * W_ + gc];
        lx[idx] = v;
    }

    // ---- Phase 0b: build table slice (threads 0..143, one tap each). ------
    if (tid < NUM_INPUTS) {
        // pos/val[(i,o,p)]: 4-channel slice = 12 floats at i*96 + g*12,
        // byte offset 384i+48g -> 16B-aligned float4s.
        const float4* pp = (const float4*)(pos + tid * 96 + g * 12);
        const float4* vv = (const float4*)(val + tid * 96 + g * 12);
        float4 pA = pp[0], pB = pp[1], pC = pp[2];
        float4 vA = vv[0], vB = vv[1], vC = vv[2];
        float P[12] = {pA.x,pA.y,pA.z,pA.w, pB.x,pB.y,pB.z,pB.w, pC.x,pC.y,pC.z,pC.w};
        float V[12] = {vA.x,vA.y,vA.z,vA.w, vB.x,vB.y,vB.z,vB.w, vC.x,vC.y,vC.z,vC.w};
        float p1[4], m0[4], dm[4], b0[4];
        #pragma unroll
        for (int k = 0; k < 4; ++k) {
            float q0 = P[3*k], q1 = P[3*k+1], q2 = P[3*k+2];
            float w0 = V[3*k], w1 = V[3*k+1], w2 = V[3*k+2];
            float s0 = (w1 - w0) / (q1 - q0);
            float s1 = (w2 - w1) / (q2 - q1);
            p1[k] = q1; m0[k] = s0; dm[k] = s1 - s0; b0[k] = w0 - s0 * q0;
        }
        ltPM[tid]              = make_float4(p1[0], p1[1], m0[0], m0[1]);
        ltD [tid]              = (f32x2){dm[0], dm[1]};
        ltB [tid]              = (f32x2){b0[0], b0[1]};
        ltPM[NUM_INPUTS + tid] = make_float4(p1[2], p1[3], m0[2], m0[3]);
        ltD [NUM_INPUTS + tid] = (f32x2){dm[2], dm[3]};
        ltB [NUM_INPUTS + tid] = (f32x2){b0[2], b0[3]};
    }
    __syncthreads();

    int col  = tid & 31;             // output col
    int trow = (tid >> 5) & 1;       // -> local output rows 2*trow, 2*trow+1
    int pgrp = (tid >> 6) & 1;       // channel pair within quad (wave-uniform)
    int cs   = tid >> 7;             // input-channel half (wave-uniform)
    int i0   = cs * 72;              // first tap of this half
    int tb0  = pgrp * NUM_INPUTS + i0;
    int base = (2 * trow) * LDS_W + col;
    int lane = tid & 63;

    // bb = sum of b0 over this (pgrp,cs) half's 72 taps, once per wave:
    // lane-parallel LDS reads (8B stride -> 2 lanes/bank, free) + butterfly.
    f32x2 bb = ltB[tb0 + lane];
    if (lane < 8) bb += ltB[tb0 + 64 + lane];
    #pragma unroll
    for (int m = 1; m < 64; m <<= 1) {
        bb.x += __shfl_xor(bb.x, m);
        bb.y += __shfl_xor(bb.y, m);
    }

    f32x2 aA = {0,0}, hA = {0,0};    // local row 2*trow
    f32x2 aB = {0,0}, hB = {0,0};    // local row 2*trow+1
    const f32x2 zz = {0.f, 0.f};

    #pragma unroll
    for (int cc = 0; cc < 8; ++cc) {
        int c = cs * 8 + cc;         // global input channel
        #pragma unroll
        for (int kw = 0; kw < 3; ++kw) {
            // 4 shared input rows cover both output rows' 3-tap kh windows.
            float p0 = lx[c * CHW + base + 0 * LDS_W + kw];
            float p1 = lx[c * CHW + base + 1 * LDS_W + kw];
            float p2 = lx[c * CHW + base + 2 * LDS_W + kw];
            float p3 = lx[c * CHW + base + 3 * LDS_W + kw];
            float pa[4] = {p0, p1, p2, p3};
            #pragma unroll
            for (int kh = 0; kh < 3; ++kh) {
                int ti = pgrp * NUM_INPUTS + (c * 3 + kh) * 3 + kw;
                float4 q = ltPM[ti];               // broadcast b128
                f32x2  D = ltD[ti];                // broadcast b64
                f32x2  P = {q.x, q.y}, M = {q.z, q.w};
                f32x2 qA = {pa[kh],     pa[kh]};
                f32x2 qB = {pa[kh + 1], pa[kh + 1]};
                aA = __builtin_elementwise_fma(M, qA, aA);
                hA = __builtin_elementwise_fma(D, __builtin_elementwise_max(qA - P, zz), hA);
                aB = __builtin_elementwise_fma(M, qB, aB);
                hB = __builtin_elementwise_fma(D, __builtin_elementwise_max(qB - P, zz), hB);
            }
        }
    }

    f32x2 rA = aA + hA + bb;         // bb: this half's Sum(b0), once per output
    f32x2 rB = aB + hB + bb;

    // ---- c-split combine: cs1 -> LDS, cs0 adds and stores. ----------------
    if (cs == 1)
        lred[tid - 128] = make_float4(rA.x, rA.y, rB.x, rB.y);
    __syncthreads();
    if (cs == 0) {
        float4 q = lred[tid];        // partner thread tid+128, same (col,trow,pgrp)
        rA.x += q.x; rA.y += q.y; rB.x += q.z; rB.y += q.w;
        int hoA = ho0 + 2 * trow;
        int o0  = 4 * g + 2 * pgrp;
        int HW  = H_ * W_;
        int ob  = ((b * OUT_CH + o0) * H_ + hoA) * W_ + col;
        out[ob          ] = rA.x;
        out[ob +      HW] = rA.y;
        out[ob + W_     ] = rB.x;
        out[ob + W_ + HW] = rB.y;
    }
}

extern "C" void kernel_launch(void* const* d_in, const int* in_sizes, int n_in,
                              void* d_out, int out_size, void* d_ws, size_t ws_size,
                              hipStream_t stream) {
    const float* x   = (const float*)d_in[0];
    const float* pos = (const float*)d_in[1];
    const float* val = (const float*)d_in[2];

    dim3 grid(64, 8);
    apc_fused<<<grid, 256, 0, stream>>>(x, pos, val, (float*)d_out);
}